// Round 1
// baseline (231.631 us; speedup 1.0000x reference)
//
#include <hip/hip_runtime.h>

// Instant-NGP hash-grid encode, odd/even two-pass, XCD-pinned, transpose-free.
//
// Schedule: pass A gathers ODD levels (XCD x -> level 2x+1) into ws[8][N]
// (nt stores). Pass B gathers EVEN levels (XCD x -> level 2x), nt-loads the
// partner odd result for the same points, and writes the final 16B chunk
// {ev.x, ev.y, od.x, od.y} straight to out + point*32 + 4x (nt store).
// This removes the 33.5MB->33.5MB transpose kernel entirely (was ~95us of
// the 220us total) and halves ws traffic. Every level's table (<=4MB) fits
// its XCD's private 4MB L2, including level 7 (previously sliced across all
// 8 XCDs -> 8x table replication in L2).
//
// Kept from previous rounds (proven):
// - x-paired 16B gathers: corners (x0,..) and (x0+1,..) share an aligned
//   16B line when x0 even -> 4 unconditional 16B + ~2 predicated 8B loads
//   per point-level (6 req avg vs 8).
// - NO agent-scope/sc0 loads (they bypass the per-XCD L2) [round 7].
// - Pin all gather results live via empty asm, else the compiler sinks
//   loads and MLP collapses [round 6].
// - nt stores for bulk output so the pinned table isn't evicted from L2.

#define HG_N_LEVELS   16
#define HG_TABLE_SIZE 524288u
#define HG_TABLE_MASK (HG_TABLE_SIZE - 1u)

typedef float vf2 __attribute__((ext_vector_type(2)));
typedef float vf4 __attribute__((ext_vector_type(4)));

// Per-point prep: 4 yz-hash partials + weights + x0.
__device__ __forceinline__ void hg_prep2(
    float px, float py, float pz, float res,
    unsigned* __restrict__ s, float* __restrict__ wyz,
    unsigned* __restrict__ x0out, float* __restrict__ wx)
{
    const float lim = 1.0f - 1e-6f;
    float ux = fminf(fmaxf(px + 0.5f, 0.0f), lim);
    float uy = fminf(fmaxf(py + 0.5f, 0.0f), lim);
    float uz = fminf(fmaxf(pz + 0.5f, 0.0f), lim);
    float fx = ux * res, fy = uy * res, fz = uz * res;
    float x0f = floorf(fx), y0f = floorf(fy), z0f = floorf(fz);
    float wx1 = fx - x0f, wy1 = fy - y0f, wz1 = fz - z0f;
    float wx0 = 1.0f - wx1, wy0 = 1.0f - wy1, wz0 = 1.0f - wz1;
    unsigned x0 = (unsigned)x0f, y0 = (unsigned)y0f, z0 = (unsigned)z0f;
    const unsigned P1 = 2654435761u, P2 = 805459861u;
    unsigned hy0 = y0 * P1, hy1 = (y0 + 1u) * P1;
    unsigned hz0 = z0 * P2, hz1 = (z0 + 1u) * P2;
    s[0] = hy0 ^ hz0;  wyz[0] = wy0 * wz0;
    s[1] = hy0 ^ hz1;  wyz[1] = wy0 * wz1;
    s[2] = hy1 ^ hz0;  wyz[2] = wy1 * wz0;
    s[3] = hy1 ^ hz1;  wyz[3] = wy1 * wz1;
    *x0out = x0; wx[0] = wx0; wx[1] = wx1;
}

// Legacy full-prep for fallback/tail paths.
__device__ __forceinline__ void hg_prep(
    float px, float py, float pz, float res,
    unsigned* __restrict__ idx, float* __restrict__ w)
{
    unsigned s[4]; float wyz[4], wx[2]; unsigned x0;
    hg_prep2(px, py, pz, res, s, wyz, &x0, wx);
    #pragma unroll
    for (int j = 0; j < 4; ++j) {
        idx[j]     = (x0 ^ s[j]) & HG_TABLE_MASK;        w[j]     = wx[0] * wyz[j];
        idx[4 + j] = ((x0 + 1u) ^ s[j]) & HG_TABLE_MASK; w[4 + j] = wx[1] * wyz[j];
    }
}

// Two-point gather for one level: returns {oax, oay, obx, oby}.
// x-paired 16B loads + predicated 8B odd loads + asm pin (proven structure).
__device__ __forceinline__ vf4 hg_gather2(
    const float2* __restrict__ tbl, float res,
    float ax, float ay, float az, float bx, float by, float bz)
{
    unsigned sA[4], sB[4], x0A, x0B;
    float wyzA[4], wyzB[4], wxA[2], wxB[2];
    hg_prep2(ax, ay, az, res, sA, wyzA, &x0A, wxA);
    hg_prep2(bx, by, bz, res, sB, wyzB, &x0B, wxB);

    unsigned iA0[4], iA1[4], iB0[4], iB1[4];
    #pragma unroll
    for (int j = 0; j < 4; ++j) {
        iA0[j] = (x0A ^ sA[j]) & HG_TABLE_MASK;
        iA1[j] = ((x0A + 1u) ^ sA[j]) & HG_TABLE_MASK;
        iB0[j] = (x0B ^ sB[j]) & HG_TABLE_MASK;
        iB1[j] = ((x0B + 1u) ^ sB[j]) & HG_TABLE_MASK;
    }
    const bool oddA = (x0A & 1u) != 0u;
    const bool oddB = (x0B & 1u) != 0u;

    // 8 unconditional 16B paired loads (line containing corner x-offset 0;
    // for even x0 the same 16B also holds corner x-offset 1).
    vf4 qA[4], qB[4];
    #pragma unroll
    for (int j = 0; j < 4; ++j) qA[j] = *(const vf4*)(tbl + (iA0[j] & ~1u));
    #pragma unroll
    for (int j = 0; j < 4; ++j) qB[j] = *(const vf4*)(tbl + (iB0[j] & ~1u));

    // predicated 8B loads of the +x corner for odd-x0 lanes only
    vf2 eA[4], eB[4];
    #pragma unroll
    for (int j = 0; j < 4; ++j) { eA[j] = (vf2)(0.f); eB[j] = (vf2)(0.f); }
    if (oddA) {
        #pragma unroll
        for (int j = 0; j < 4; ++j) eA[j] = *(const vf2*)(tbl + iA1[j]);
    }
    if (oddB) {
        #pragma unroll
        for (int j = 0; j < 4; ++j) eB[j] = *(const vf2*)(tbl + iB1[j]);
    }

    // Pin everything simultaneously live -> loads can't sink, MLP stays up.
    asm volatile(""
        : "+v"(qA[0]), "+v"(qA[1]), "+v"(qA[2]), "+v"(qA[3]),
          "+v"(qB[0]), "+v"(qB[1]), "+v"(qB[2]), "+v"(qB[3]),
          "+v"(eA[0]), "+v"(eA[1]), "+v"(eA[2]), "+v"(eA[3]),
          "+v"(eB[0]), "+v"(eB[1]), "+v"(eB[2]), "+v"(eB[3])
        :
        : "memory");

    float oax = 0.f, oay = 0.f, obx = 0.f, oby = 0.f;
    #pragma unroll
    for (int j = 0; j < 4; ++j) {
        bool hi = (iA0[j] & 1u) != 0u;
        vf2 lo;  lo.x  = qA[j].x; lo.y  = qA[j].y;
        vf2 hiv; hiv.x = qA[j].z; hiv.y = qA[j].w;
        vf2 f0 = hi ? hiv : lo;                  // corner x-offset 0
        vf2 f1 = oddA ? eA[j] : (hi ? lo : hiv); // corner x-offset 1
        float w0 = wxA[0] * wyzA[j], w1 = wxA[1] * wyzA[j];
        oax += w0 * f0.x + w1 * f1.x;
        oay += w0 * f0.y + w1 * f1.y;
    }
    #pragma unroll
    for (int j = 0; j < 4; ++j) {
        bool hi = (iB0[j] & 1u) != 0u;
        vf2 lo;  lo.x  = qB[j].x; lo.y  = qB[j].y;
        vf2 hiv; hiv.x = qB[j].z; hiv.y = qB[j].w;
        vf2 f0 = hi ? hiv : lo;
        vf2 f1 = oddB ? eB[j] : (hi ? lo : hiv);
        float w0 = wxB[0] * wyzB[j], w1 = wxB[1] * wyzB[j];
        obx += w0 * f0.x + w1 * f1.x;
        oby += w0 * f0.y + w1 * f1.y;
    }

    vf4 r; r.x = oax; r.y = oay; r.z = obx; r.w = oby;
    return r;
}

// Scalar single-point gather (tail path).
__device__ __forceinline__ vf2 hg_gather1(
    const float2* __restrict__ tbl, float res,
    float px, float py, float pz)
{
    unsigned idx[8]; float w[8];
    hg_prep(px, py, pz, res, idx, w);
    vf2 f[8];
    #pragma unroll
    for (int k = 0; k < 8; ++k) f[k] = *(const vf2*)(tbl + idx[k]);
    float sx = 0.f, sy = 0.f;
    #pragma unroll
    for (int k = 0; k < 8; ++k) { sx += w[k] * f[k].x; sy += w[k] * f[k].y; }
    vf2 v; v.x = sx; v.y = sy;
    return v;
}

// ---------- Pass A: odd levels -> ws[8][N] float2 ----------
__global__ __launch_bounds__(256) void hashgrid_pa(
    const float* __restrict__ xyz,
    const float* __restrict__ tables,
    const int*   __restrict__ resolutions,
    float*       __restrict__ ws,       // [8][n] float2, as floats
    int n_points)
{
    const int x     = blockIdx.x & 7;    // XCD (blockIdx%8 round-robin)
    const int chunk = blockIdx.x >> 3;   // 512-point chunk
    const int level = 2 * x + 1;

    const float res = (float)resolutions[level];
    const float2* __restrict__ tbl =
        (const float2*)tables + (size_t)level * HG_TABLE_SIZE;
    float* __restrict__ wrow = ws + (size_t)x * n_points * 2;

    const int p0 = (chunk << 9) + ((int)threadIdx.x << 1);   // 2 pts/thread
    if (p0 >= n_points) return;

    if (p0 + 1 < n_points) {
        const float* xp = xyz + (size_t)p0 * 3;
        vf2 c0 = *(const vf2*)(xp);
        vf2 c1 = *(const vf2*)(xp + 2);
        vf2 c2 = *(const vf2*)(xp + 4);
        vf4 v = hg_gather2(tbl, res, c0.x, c0.y, c1.x, c1.y, c2.x, c2.y);
        __builtin_nontemporal_store(v, (vf4*)(wrow + 2 * (size_t)p0)); // 16B aligned
    } else {
        vf2 v = hg_gather1(tbl, res,
                           xyz[(size_t)p0 * 3 + 0],
                           xyz[(size_t)p0 * 3 + 1],
                           xyz[(size_t)p0 * 3 + 2]);
        __builtin_nontemporal_store(v, (vf2*)(wrow + 2 * (size_t)p0));
    }
}

// ---------- Pass B: even levels + combine with odd partner -> out ----------
__global__ __launch_bounds__(256) void hashgrid_pb(
    const float* __restrict__ xyz,
    const float* __restrict__ tables,
    const int*   __restrict__ resolutions,
    const float* __restrict__ ws,
    float*       __restrict__ out,      // [n][32] floats
    int n_points)
{
    const int x     = blockIdx.x & 7;
    const int chunk = blockIdx.x >> 3;
    const int level = 2 * x;             // partner odd level 2x+1 is ws row x

    const float res = (float)resolutions[level];
    const float2* __restrict__ tbl =
        (const float2*)tables + (size_t)level * HG_TABLE_SIZE;
    const float* __restrict__ wrow = ws + (size_t)x * n_points * 2;

    const int p0 = (chunk << 9) + ((int)threadIdx.x << 1);
    if (p0 >= n_points) return;

    if (p0 + 1 < n_points) {
        // Issue the partner-odd load first (streaming, nt -> no L2 pollution
        // of the pinned even table), pin it so it can't sink.
        vf4 wsv = __builtin_nontemporal_load((const vf4*)(wrow + 2 * (size_t)p0));
        asm volatile("" : "+v"(wsv));

        const float* xp = xyz + (size_t)p0 * 3;
        vf2 c0 = *(const vf2*)(xp);
        vf2 c1 = *(const vf2*)(xp + 2);
        vf2 c2 = *(const vf2*)(xp + 4);
        vf4 g = hg_gather2(tbl, res, c0.x, c0.y, c1.x, c1.y, c2.x, c2.y);

        // out row = 32 floats; pair x owns floats [4x, 4x+4):
        // even level 2x -> cols 4x,4x+1; odd level 2x+1 -> cols 4x+2,4x+3.
        vf4 o0; o0.x = g.x; o0.y = g.y; o0.z = wsv.x; o0.w = wsv.y;
        vf4 o1; o1.x = g.z; o1.y = g.w; o1.z = wsv.z; o1.w = wsv.w;
        float* op = out + (size_t)p0 * 32 + 4 * x;       // 16B aligned
        __builtin_nontemporal_store(o0, (vf4*)op);
        __builtin_nontemporal_store(o1, (vf4*)(op + 32));
    } else {
        vf2 wsv = __builtin_nontemporal_load((const vf2*)(wrow + 2 * (size_t)p0));
        vf2 g = hg_gather1(tbl, res,
                           xyz[(size_t)p0 * 3 + 0],
                           xyz[(size_t)p0 * 3 + 1],
                           xyz[(size_t)p0 * 3 + 2]);
        vf4 o; o.x = g.x; o.y = g.y; o.z = wsv.x; o.w = wsv.y;
        __builtin_nontemporal_store(o, (vf4*)(out + (size_t)p0 * 32 + 4 * x));
    }
}

// ---------- Fallback: single-kernel version (ws too small) ----------
__global__ __launch_bounds__(256) void hashgrid_fwd(
    const float* __restrict__ xyz,
    const float* __restrict__ tables,
    const int*   __restrict__ resolutions,
    float*       __restrict__ out,
    int n_points)
{
    int tid   = blockIdx.x * blockDim.x + threadIdx.x;
    int point = tid >> 4;
    int level = tid & 15;
    if (point >= n_points) return;

    float px = xyz[point * 3 + 0];
    float py = xyz[point * 3 + 1];
    float pz = xyz[point * 3 + 2];
    float res = (float)resolutions[level];
    const float2* __restrict__ tbl =
        (const float2*)tables + (size_t)level * HG_TABLE_SIZE;

    vf2 v = hg_gather1(tbl, res, px, py, pz);
    *(vf2*)(out + (size_t)point * 32 + 2 * level) = v;
}

extern "C" void kernel_launch(void* const* d_in, const int* in_sizes, int n_in,
                              void* d_out, int out_size, void* d_ws, size_t ws_size,
                              hipStream_t stream) {
    const float* xyz         = (const float*)d_in[0];
    const float* tables      = (const float*)d_in[1];
    const int*   resolutions = (const int*)d_in[2];
    float*       out         = (float*)d_out;

    int n_points = in_sizes[0] / 3;
    size_t ws_needed = (size_t)n_points * 8 * sizeof(float2);  // 8 odd rows

    if (ws_size >= ws_needed) {
        float* ws = (float*)d_ws;
        int C = (n_points + 511) >> 9;          // 512-point chunks
        hashgrid_pa<<<8 * C, 256, 0, stream>>>(
            xyz, tables, resolutions, ws, n_points);
        hashgrid_pb<<<8 * C, 256, 0, stream>>>(
            xyz, tables, resolutions, ws, out, n_points);
    } else {
        int n_threads = n_points * HG_N_LEVELS;
        hashgrid_fwd<<<(n_threads + 255) / 256, 256, 0, stream>>>(
            xyz, tables, resolutions, out, n_points);
    }
}